// Round 3
// baseline (402.885 us; speedup 1.0000x reference)
//
#include <hip/hip_runtime.h>

typedef unsigned short u16;
typedef __attribute__((ext_vector_type(8))) short bf16x8;   // 8 bf16 in 4 VGPRs
typedef __attribute__((ext_vector_type(4))) float f32x4;
typedef __attribute__((ext_vector_type(4))) unsigned short u16x4;
typedef __attribute__((ext_vector_type(2))) unsigned short u16x2;

__device__ __forceinline__ u16 f2bf(float f) {
    unsigned int u = __builtin_bit_cast(unsigned int, f);
    u += 0x7fffu + ((u >> 16) & 1u);          // round-to-nearest-even
    return (u16)(u >> 16);
}

__device__ __forceinline__ void gload_lds16(const u16* g, const u16* l) {
    __builtin_amdgcn_global_load_lds((const __attribute__((address_space(1))) void*)g,
                                     (__attribute__((address_space(3))) void*)l,
                                     16, 0, 0);
}

// ---------------- fp32 -> bf16 conversion ----------------
__global__ __launch_bounds__(256) void cvt_f32_bf16(const float* __restrict__ in,
                                                    u16* __restrict__ out, int n4) {
    int i = blockIdx.x * blockDim.x + threadIdx.x;
    int stride = gridDim.x * blockDim.x;
    for (; i < n4; i += stride) {
        float4 v = reinterpret_cast<const float4*>(in)[i];
        u16x4 o = { f2bf(v.x), f2bf(v.y), f2bf(v.z), f2bf(v.w) };
        reinterpret_cast<u16x4*>(out)[i] = o;
    }
}

// ---------------- bf16 GEMM: C[m,n] = sum_k A[m,k] * B[n,k] ----------------
// 128x128 tile, BK=64, 256 threads = 4 waves (2x2), each wave 64x64 via 4x4 of 16x16x32.
template <typename OutT>
__global__ __launch_bounds__(256) void gemm_bt(const u16* __restrict__ A, const u16* __restrict__ B,
                                               OutT* __restrict__ C, int M, int N, int K) {
    __shared__ u16 ldsA[128 * 64];
    __shared__ u16 ldsB[128 * 64];
    const int tid = threadIdx.x;
    const int lane = tid & 63;
    const int wid = tid >> 6;
    const int wm = wid >> 1, wn = wid & 1;
    const int lq = lane & 15, lg = lane >> 4;
    const int bm = blockIdx.y * 128, bn = blockIdx.x * 128;

    // staging sources: 1024 chunks of 16B per tile half, 4 rounds of 256 threads
    const u16* aSrc[4];
    const u16* bSrc[4];
    int dstOff[4];
#pragma unroll
    for (int j = 0; j < 4; ++j) {
        int item = j * 256 + tid;          // 0..1023
        int row = item >> 3;               // tile row (0..127)
        int c16 = item & 7;                // 16B chunk within 128B row
        aSrc[j] = A + (size_t)(bm + row) * K + c16 * 8;
        bSrc[j] = B + (size_t)(bn + row) * K + c16 * 8;
        dstOff[j] = (j * 256 + (tid & ~63)) * 16;   // wave-uniform LDS byte base
    }

    f32x4 acc[4][4] = {};
    for (int k0 = 0; k0 < K; k0 += 64) {
        if (k0) __syncthreads();
#pragma unroll
        for (int j = 0; j < 4; ++j) {
            gload_lds16(aSrc[j], (const u16*)((const char*)ldsA + dstOff[j]));
            gload_lds16(bSrc[j], (const u16*)((const char*)ldsB + dstOff[j]));
            aSrc[j] += 64;
            bSrc[j] += 64;
        }
        __syncthreads();
#pragma unroll
        for (int kk = 0; kk < 2; ++kk) {
            bf16x8 af[4], bfr[4];
#pragma unroll
            for (int m = 0; m < 4; ++m) {
                int row = wm * 64 + m * 16 + lq;
                af[m] = *(const bf16x8*)((const char*)ldsA + row * 128 + kk * 64 + lg * 16);
            }
#pragma unroll
            for (int n = 0; n < 4; ++n) {
                int row = wn * 64 + n * 16 + lq;
                bfr[n] = *(const bf16x8*)((const char*)ldsB + row * 128 + kk * 64 + lg * 16);
            }
#pragma unroll
            for (int m = 0; m < 4; ++m)
#pragma unroll
                for (int n = 0; n < 4; ++n)
                    acc[m][n] = __builtin_amdgcn_mfma_f32_16x16x32_bf16(af[m], bfr[n], acc[m][n], 0, 0, 0);
        }
    }

    // epilogue: C/D layout col = lane&15, row = (lane>>4)*4 + reg
#pragma unroll
    for (int m = 0; m < 4; ++m) {
#pragma unroll
        for (int n = 0; n < 4; ++n) {
#pragma unroll
            for (int r = 0; r < 4; ++r) {
                int row = bm + wm * 64 + m * 16 + lg * 4 + r;
                int col = bn + wn * 64 + n * 16 + lq;
                float v = acc[m][n][r];
                if constexpr (sizeof(OutT) == 2)
                    C[(size_t)row * N + col] = (OutT)f2bf(v);
                else
                    C[(size_t)row * N + col] = (OutT)v;
            }
        }
    }
}

// ---------------- transpose V: (B,T,[v]H,hd) -> (B,H,hd,T) ----------------
__global__ __launch_bounds__(256) void transpose_v(const u16* __restrict__ qkv, u16* __restrict__ vt) {
    __shared__ u16 tile[64][72];    // +8 pad
    const int tb = blockIdx.x * 64;
    const int bh = blockIdx.y;      // b*16+h
    const int b = bh >> 4, h = bh & 15;
    const u16* src = qkv + ((size_t)(b * 2048 + tb)) * 3072 + 2048 + h * 64;
    const int tid = threadIdx.x;
#pragma unroll
    for (int p = 0; p < 2; ++p) {
        int item = p * 256 + tid;
        int t = item >> 3, c = item & 7;
        bf16x8 v = *(const bf16x8*)(src + (size_t)t * 3072 + c * 8);
        *(bf16x8*)(&tile[t][c * 8]) = v;
    }
    __syncthreads();
    u16* dst = vt + ((size_t)bh * 64) * 2048 + tb;
#pragma unroll
    for (int p = 0; p < 2; ++p) {
        int item = p * 256 + tid;
        int d = item >> 3, tc = item & 7;
        bf16x8 o;
#pragma unroll
        for (int j = 0; j < 8; ++j) o[j] = (short)tile[tc * 8 + j][d];
        *(bf16x8*)(dst + (size_t)d * 2048 + tc * 8) = o;
    }
}

// ---------------- flash attention, causal, hd=64 ----------------
// block = 4 independent waves; wave w owns 16 q-rows. Swapped QK^T: S^T = K * Q^T.
__global__ __launch_bounds__(256) void fhn_attn(const u16* __restrict__ qkv, const u16* __restrict__ vt,
                                                u16* __restrict__ attno) {
    __shared__ u16 plds[4][16][72];         // per-wave P tile, +8 pad
    const int qtile = gridDim.x - 1 - blockIdx.x;   // heavy tiles first
    const int bh = blockIdx.y;
    const int b = bh >> 4, h = bh & 15;
    const int tid = threadIdx.x;
    const int w = tid >> 6;
    const int lane = tid & 63;
    const int lq = lane & 15, lg = lane >> 4;

    const int tq = qtile * 64 + w * 16 + lq;    // softmax row owned by this lane
    const u16* qrow = qkv + ((size_t)(b * 2048 + tq)) * 3072 + h * 64;
    bf16x8 qf[2];
    qf[0] = *(const bf16x8*)(qrow + lg * 8);
    qf[1] = *(const bf16x8*)(qrow + 32 + lg * 8);

    const u16* kbase = qkv + ((size_t)(b * 2048)) * 3072 + 1024 + h * 64;
    const u16* vbase = vt + ((size_t)bh * 64) * 2048;

    float m_run = -1e30f, l_run = 0.f;
    f32x4 oacc[4] = {};
    const int nkv = qtile + 1;
    for (int jb = 0; jb < nkv; ++jb) {
        const int sb = jb * 64;
        const bool lastb = (jb == nkv - 1);

        // S^T = K * Q^T  (A-frag row = s = lane&15; B-frag col = q = lane&15)
        float p[4][4];
        float mloc = -1e30f;
#pragma unroll
        for (int st = 0; st < 4; ++st) {
            f32x4 sacc = {};
            const u16* kptr = kbase + ((size_t)(sb + st * 16 + lq)) * 3072 + lg * 8;
            sacc = __builtin_amdgcn_mfma_f32_16x16x32_bf16(*(const bf16x8*)kptr, qf[0], sacc, 0, 0, 0);
            sacc = __builtin_amdgcn_mfma_f32_16x16x32_bf16(*(const bf16x8*)(kptr + 32), qf[1], sacc, 0, 0, 0);
#pragma unroll
            for (int r = 0; r < 4; ++r) {
                int s = sb + st * 16 + lg * 4 + r;      // output row = s
                float sc = sacc[r] * 0.125f;            // 1/sqrt(64)
                if (lastb && s > tq) sc = -1e30f;
                p[st][r] = sc;
                mloc = fmaxf(mloc, sc);
            }
        }
        // row stats live on 4 lanes (lg=0..3) sharing lq: butterfly over bits 4,5
        mloc = fmaxf(mloc, __shfl_xor(mloc, 16));
        mloc = fmaxf(mloc, __shfl_xor(mloc, 32));
        float mnew = fmaxf(m_run, mloc);
        float scale_prev = exp2f((m_run - mnew) * 1.44269504f);

        float lloc = 0.f;
#pragma unroll
        for (int st = 0; st < 4; ++st)
#pragma unroll
            for (int r = 0; r < 4; ++r) {
                float e = exp2f((p[st][r] - mnew) * 1.44269504f);
                p[st][r] = e;
                lloc += e;
            }
        lloc += __shfl_xor(lloc, 16);
        lloc += __shfl_xor(lloc, 32);
        l_run = l_run * scale_prev + lloc;
        m_run = mnew;

        // write P^T back as P: P_lds[q][s] (bf16, packed pairs)
#pragma unroll
        for (int st = 0; st < 4; ++st)
#pragma unroll
            for (int rp = 0; rp < 2; ++rp) {
                u16x2 pk = { f2bf(p[st][2 * rp]), f2bf(p[st][2 * rp + 1]) };
                *(u16x2*)(&plds[w][lq][st * 16 + lg * 4 + 2 * rp]) = pk;
            }

        // rescale running O: PV output rows are q = lg*4 + r, fetch factors via shfl
        float f0 = __shfl(scale_prev, lg * 4 + 0);
        float f1 = __shfl(scale_prev, lg * 4 + 1);
        float f2_ = __shfl(scale_prev, lg * 4 + 2);
        float f3 = __shfl(scale_prev, lg * 4 + 3);
#pragma unroll
        for (int nd = 0; nd < 4; ++nd) {
            oacc[nd][0] *= f0; oacc[nd][1] *= f1; oacc[nd][2] *= f2_; oacc[nd][3] *= f3;
        }

        // PV: O += P * V   (A-frag row = q = lane&15 from LDS; B-frag col = d from Vt)
#pragma unroll
        for (int c = 0; c < 2; ++c) {
            bf16x8 pa = *(const bf16x8*)(&plds[w][lq][c * 32 + lg * 8]);
#pragma unroll
            for (int nd = 0; nd < 4; ++nd) {
                const u16* vptr = vbase + ((size_t)(nd * 16 + lq)) * 2048 + sb + c * 32 + lg * 8;
                oacc[nd] = __builtin_amdgcn_mfma_f32_16x16x32_bf16(pa, *(const bf16x8*)vptr, oacc[nd], 0, 0, 0);
            }
        }
    }

    // epilogue: divide by l (per output row q = lg*4+r), store bf16 (B,T,H*hd)
    float li0 = 1.f / __shfl(l_run, lg * 4 + 0);
    float li1 = 1.f / __shfl(l_run, lg * 4 + 1);
    float li2 = 1.f / __shfl(l_run, lg * 4 + 2);
    float li3 = 1.f / __shfl(l_run, lg * 4 + 3);
#pragma unroll
    for (int nd = 0; nd < 4; ++nd) {
#pragma unroll
        for (int r = 0; r < 4; ++r) {
            int trow = qtile * 64 + w * 16 + lg * 4 + r;
            float li = (r == 0) ? li0 : (r == 1) ? li1 : (r == 2) ? li2 : li3;
            attno[((size_t)(b * 2048 + trow)) * 1024 + h * 64 + nd * 16 + lq] = f2bf(oacc[nd][r] * li);
        }
    }
}

extern "C" void kernel_launch(void* const* d_in, const int* in_sizes, int n_in,
                              void* d_out, int out_size, void* d_ws, size_t ws_size,
                              hipStream_t stream) {
    const float* x    = (const float*)d_in[0];   // (2,2048,1024)
    const float* Wqkv = (const float*)d_in[1];   // (3072,1024)
    const float* Wout = (const float*)d_in[2];   // (1024,1024)
    float* out = (float*)d_out;

    char* ws = (char*)d_ws;
    u16* xb    = (u16*)(ws + 0);           //  8,388,608 B
    u16* wqkvb = (u16*)(ws + 8388608);     //  6,291,456 B
    u16* woutb = (u16*)(ws + 14680064);    //  2,097,152 B
    u16* qkvb  = (u16*)(ws + 16777216);    // 25,165,824 B
    u16* vtb   = (u16*)(ws + 41943040);    //  8,388,608 B
    u16* attno = (u16*)(ws + 50331648);    //  8,388,608 B  (end 58,720,256)

    cvt_f32_bf16<<<2048, 256, 0, stream>>>(x, xb, 4194304 / 4);
    cvt_f32_bf16<<<2048, 256, 0, stream>>>(Wqkv, wqkvb, 3145728 / 4);
    cvt_f32_bf16<<<1024, 256, 0, stream>>>(Wout, woutb, 1048576 / 4);

    gemm_bt<u16><<<dim3(24, 32), 256, 0, stream>>>(xb, wqkvb, qkvb, 4096, 3072, 1024);

    transpose_v<<<dim3(32, 32), 256, 0, stream>>>(qkvb, vtb);

    fhn_attn<<<dim3(32, 32), 256, 0, stream>>>(qkvb, vtb, attno);

    gemm_bt<float><<<dim3(8, 32), 256, 0, stream>>>(attno, woutb, out, 4096, 1024, 1024);
}

// Round 4
// 399.640 us; speedup vs baseline: 1.0081x; 1.0081x over previous
//
#include <hip/hip_runtime.h>

typedef unsigned short u16;
typedef __attribute__((ext_vector_type(8))) short bf16x8;   // 8 bf16 in 4 VGPRs
typedef __attribute__((ext_vector_type(4))) float f32x4;
typedef __attribute__((ext_vector_type(4))) unsigned short u16x4;
typedef __attribute__((ext_vector_type(2))) unsigned short u16x2;

__device__ __forceinline__ u16 f2bf(float f) {
    unsigned int u = __builtin_bit_cast(unsigned int, f);
    u += 0x7fffu + ((u >> 16) & 1u);          // round-to-nearest-even
    return (u16)(u >> 16);
}

__device__ __forceinline__ void gload_lds16(const u16* g, const u16* l) {
    __builtin_amdgcn_global_load_lds((const __attribute__((address_space(1))) void*)g,
                                     (__attribute__((address_space(3))) void*)l,
                                     16, 0, 0);
}

// ---------------- fp32 -> bf16 conversion ----------------
__global__ __launch_bounds__(256) void cvt_f32_bf16(const float* __restrict__ in,
                                                    u16* __restrict__ out, int n4) {
    int i = blockIdx.x * blockDim.x + threadIdx.x;
    int stride = gridDim.x * blockDim.x;
    for (; i < n4; i += stride) {
        float4 v = reinterpret_cast<const float4*>(in)[i];
        u16x4 o = { f2bf(v.x), f2bf(v.y), f2bf(v.z), f2bf(v.w) };
        reinterpret_cast<u16x4*>(out)[i] = o;
    }
}

// ---------------- bf16 GEMM: C[m,n] = sum_k A[m,k] * B[n,k] ----------------
// 128x128 tile, BK=64, 256 threads = 4 waves (2x2), each wave 64x64 via 4x4 of 16x16x32.
template <typename OutT>
__global__ __launch_bounds__(256) void gemm_bt(const u16* __restrict__ A, const u16* __restrict__ B,
                                               OutT* __restrict__ C, int M, int N, int K) {
    __shared__ u16 ldsA[128 * 64];
    __shared__ u16 ldsB[128 * 64];
    const int tid = threadIdx.x;
    const int lane = tid & 63;
    const int wid = tid >> 6;
    const int wm = wid >> 1, wn = wid & 1;
    const int lq = lane & 15, lg = lane >> 4;
    const int bm = blockIdx.y * 128, bn = blockIdx.x * 128;

    // staging sources: 1024 chunks of 16B per tile half, 4 rounds of 256 threads
    const u16* aSrc[4];
    const u16* bSrc[4];
    int dstOff[4];
#pragma unroll
    for (int j = 0; j < 4; ++j) {
        int item = j * 256 + tid;          // 0..1023
        int row = item >> 3;               // tile row (0..127)
        int c16 = item & 7;                // 16B chunk within 128B row
        aSrc[j] = A + (size_t)(bm + row) * K + c16 * 8;
        bSrc[j] = B + (size_t)(bn + row) * K + c16 * 8;
        dstOff[j] = (j * 256 + (tid & ~63)) * 16;   // wave-uniform LDS byte base
    }

    f32x4 acc[4][4] = {};
    for (int k0 = 0; k0 < K; k0 += 64) {
        if (k0) __syncthreads();
#pragma unroll
        for (int j = 0; j < 4; ++j) {
            gload_lds16(aSrc[j], (const u16*)((const char*)ldsA + dstOff[j]));
            gload_lds16(bSrc[j], (const u16*)((const char*)ldsB + dstOff[j]));
            aSrc[j] += 64;
            bSrc[j] += 64;
        }
        __syncthreads();
#pragma unroll
        for (int kk = 0; kk < 2; ++kk) {
            bf16x8 af[4], bfr[4];
#pragma unroll
            for (int m = 0; m < 4; ++m) {
                int row = wm * 64 + m * 16 + lq;
                af[m] = *(const bf16x8*)((const char*)ldsA + row * 128 + kk * 64 + lg * 16);
            }
#pragma unroll
            for (int n = 0; n < 4; ++n) {
                int row = wn * 64 + n * 16 + lq;
                bfr[n] = *(const bf16x8*)((const char*)ldsB + row * 128 + kk * 64 + lg * 16);
            }
#pragma unroll
            for (int m = 0; m < 4; ++m)
#pragma unroll
                for (int n = 0; n < 4; ++n)
                    acc[m][n] = __builtin_amdgcn_mfma_f32_16x16x32_bf16(af[m], bfr[n], acc[m][n], 0, 0, 0);
        }
    }

    // epilogue: C/D layout col = lane&15, row = (lane>>4)*4 + reg
#pragma unroll
    for (int m = 0; m < 4; ++m) {
#pragma unroll
        for (int n = 0; n < 4; ++n) {
#pragma unroll
            for (int r = 0; r < 4; ++r) {
                int row = bm + wm * 64 + m * 16 + lg * 4 + r;
                int col = bn + wn * 64 + n * 16 + lq;
                float v = acc[m][n][r];
                if constexpr (sizeof(OutT) == 2)
                    C[(size_t)row * N + col] = (OutT)f2bf(v);
                else
                    C[(size_t)row * N + col] = (OutT)v;
            }
        }
    }
}

// ---------------- transpose V: (B,T,[v]H,hd) -> (B,H,hd,T) ----------------
__global__ __launch_bounds__(256) void transpose_v(const u16* __restrict__ qkv, u16* __restrict__ vt) {
    __shared__ u16 tile[64][72];    // +8 pad
    const int tb = blockIdx.x * 64;
    const int bh = blockIdx.y;      // b*16+h
    const int b = bh >> 4, h = bh & 15;
    const u16* src = qkv + ((size_t)(b * 2048 + tb)) * 3072 + 2048 + h * 64;
    const int tid = threadIdx.x;
#pragma unroll
    for (int p = 0; p < 2; ++p) {
        int item = p * 256 + tid;
        int t = item >> 3, c = item & 7;
        bf16x8 v = *(const bf16x8*)(src + (size_t)t * 3072 + c * 8);
        *(bf16x8*)(&tile[t][c * 8]) = v;
    }
    __syncthreads();
    u16* dst = vt + ((size_t)bh * 64) * 2048 + tb;
#pragma unroll
    for (int p = 0; p < 2; ++p) {
        int item = p * 256 + tid;
        int d = item >> 3, tc = item & 7;
        bf16x8 o;
#pragma unroll
        for (int j = 0; j < 8; ++j) o[j] = (short)tile[tc * 8 + j][d];
        *(bf16x8*)(dst + (size_t)d * 2048 + tc * 8) = o;
    }
}

// ---------------- flash attention, causal, hd=64 ----------------
// block = 4 independent waves; wave w owns 16 q-rows. Swapped QK^T: S^T = K * Q^T.
__global__ __launch_bounds__(256) void fhn_attn(const u16* __restrict__ qkv, const u16* __restrict__ vt,
                                                u16* __restrict__ attno) {
    __shared__ u16 plds[4][16][72];         // per-wave P tile, +8 pad
    const int qtile = gridDim.x - 1 - blockIdx.x;   // heavy tiles first
    const int bh = blockIdx.y;
    const int b = bh >> 4, h = bh & 15;
    const int tid = threadIdx.x;
    const int w = tid >> 6;
    const int lane = tid & 63;
    const int lq = lane & 15, lg = lane >> 4;

    const int tq = qtile * 64 + w * 16 + lq;    // softmax row owned by this lane
    const u16* qrow = qkv + ((size_t)(b * 2048 + tq)) * 3072 + h * 64;
    bf16x8 qf[2];
    qf[0] = *(const bf16x8*)(qrow + lg * 8);
    qf[1] = *(const bf16x8*)(qrow + 32 + lg * 8);

    const u16* kbase = qkv + ((size_t)(b * 2048)) * 3072 + 1024 + h * 64;
    const u16* vbase = vt + ((size_t)bh * 64) * 2048;

    float m_run = -1e30f, l_run = 0.f;
    f32x4 oacc[4] = {};
    const int nkv = qtile + 1;
    for (int jb = 0; jb < nkv; ++jb) {
        const int sb = jb * 64;
        const bool lastb = (jb == nkv - 1);

        // S^T = K * Q^T  (A-frag row = s = lane&15; B-frag col = q = lane&15)
        float p[4][4];
        float mloc = -1e30f;
#pragma unroll
        for (int st = 0; st < 4; ++st) {
            f32x4 sacc = {};
            const u16* kptr = kbase + ((size_t)(sb + st * 16 + lq)) * 3072 + lg * 8;
            sacc = __builtin_amdgcn_mfma_f32_16x16x32_bf16(*(const bf16x8*)kptr, qf[0], sacc, 0, 0, 0);
            sacc = __builtin_amdgcn_mfma_f32_16x16x32_bf16(*(const bf16x8*)(kptr + 32), qf[1], sacc, 0, 0, 0);
#pragma unroll
            for (int r = 0; r < 4; ++r) {
                int s = sb + st * 16 + lg * 4 + r;      // output row = s
                float sc = sacc[r] * 0.125f;            // 1/sqrt(64)
                if (lastb && s > tq) sc = -1e30f;
                p[st][r] = sc;
                mloc = fmaxf(mloc, sc);
            }
        }
        // row stats live on 4 lanes (lg=0..3) sharing lq: butterfly over bits 4,5
        mloc = fmaxf(mloc, __shfl_xor(mloc, 16));
        mloc = fmaxf(mloc, __shfl_xor(mloc, 32));
        float mnew = fmaxf(m_run, mloc);
        float scale_prev = exp2f((m_run - mnew) * 1.44269504f);

        float lloc = 0.f;
#pragma unroll
        for (int st = 0; st < 4; ++st)
#pragma unroll
            for (int r = 0; r < 4; ++r) {
                float e = exp2f((p[st][r] - mnew) * 1.44269504f);
                p[st][r] = e;
                lloc += e;
            }
        lloc += __shfl_xor(lloc, 16);
        lloc += __shfl_xor(lloc, 32);
        l_run = l_run * scale_prev + lloc;
        m_run = mnew;

        // write P^T back as P: P_lds[q][s] (bf16, packed pairs)
#pragma unroll
        for (int st = 0; st < 4; ++st)
#pragma unroll
            for (int rp = 0; rp < 2; ++rp) {
                u16x2 pk = { f2bf(p[st][2 * rp]), f2bf(p[st][2 * rp + 1]) };
                *(u16x2*)(&plds[w][lq][st * 16 + lg * 4 + 2 * rp]) = pk;
            }

        // rescale running O: PV output rows are q = lg*4 + r, fetch factors via shfl
        float f0 = __shfl(scale_prev, lg * 4 + 0);
        float f1 = __shfl(scale_prev, lg * 4 + 1);
        float f2_ = __shfl(scale_prev, lg * 4 + 2);
        float f3 = __shfl(scale_prev, lg * 4 + 3);
#pragma unroll
        for (int nd = 0; nd < 4; ++nd) {
            oacc[nd][0] *= f0; oacc[nd][1] *= f1; oacc[nd][2] *= f2_; oacc[nd][3] *= f3;
        }

        // PV: O += P * V   (A-frag row = q = lane&15 from LDS; B-frag col = d from Vt)
#pragma unroll
        for (int c = 0; c < 2; ++c) {
            bf16x8 pa = *(const bf16x8*)(&plds[w][lq][c * 32 + lg * 8]);
#pragma unroll
            for (int nd = 0; nd < 4; ++nd) {
                const u16* vptr = vbase + ((size_t)(nd * 16 + lq)) * 2048 + sb + c * 32 + lg * 8;
                oacc[nd] = __builtin_amdgcn_mfma_f32_16x16x32_bf16(pa, *(const bf16x8*)vptr, oacc[nd], 0, 0, 0);
            }
        }
    }

    // epilogue: divide by l (per output row q = lg*4+r), store bf16 (B,T,H*hd)
    float li0 = 1.f / __shfl(l_run, lg * 4 + 0);
    float li1 = 1.f / __shfl(l_run, lg * 4 + 1);
    float li2 = 1.f / __shfl(l_run, lg * 4 + 2);
    float li3 = 1.f / __shfl(l_run, lg * 4 + 3);
#pragma unroll
    for (int nd = 0; nd < 4; ++nd) {
#pragma unroll
        for (int r = 0; r < 4; ++r) {
            int trow = qtile * 64 + w * 16 + lg * 4 + r;
            float li = (r == 0) ? li0 : (r == 1) ? li1 : (r == 2) ? li2 : li3;
            attno[((size_t)(b * 2048 + trow)) * 1024 + h * 64 + nd * 16 + lq] = f2bf(oacc[nd][r] * li);
        }
    }
}

extern "C" void kernel_launch(void* const* d_in, const int* in_sizes, int n_in,
                              void* d_out, int out_size, void* d_ws, size_t ws_size,
                              hipStream_t stream) {
    const float* x    = (const float*)d_in[0];   // (2,2048,1024)
    const float* Wqkv = (const float*)d_in[1];   // (3072,1024)
    const float* Wout = (const float*)d_in[2];   // (1024,1024)
    float* out = (float*)d_out;

    char* ws = (char*)d_ws;
    u16* xb    = (u16*)(ws + 0);           //  8,388,608 B
    u16* wqkvb = (u16*)(ws + 8388608);     //  6,291,456 B
    u16* woutb = (u16*)(ws + 14680064);    //  2,097,152 B
    u16* qkvb  = (u16*)(ws + 16777216);    // 25,165,824 B
    u16* vtb   = (u16*)(ws + 41943040);    //  8,388,608 B
    u16* attno = (u16*)(ws + 50331648);    //  8,388,608 B  (end 58,720,256)

    cvt_f32_bf16<<<2048, 256, 0, stream>>>(x, xb, 4194304 / 4);
    cvt_f32_bf16<<<2048, 256, 0, stream>>>(Wqkv, wqkvb, 3145728 / 4);
    cvt_f32_bf16<<<1024, 256, 0, stream>>>(Wout, woutb, 1048576 / 4);

    gemm_bt<u16><<<dim3(24, 32), 256, 0, stream>>>(xb, wqkvb, qkvb, 4096, 3072, 1024);

    transpose_v<<<dim3(32, 32), 256, 0, stream>>>(qkvb, vtb);

    fhn_attn<<<dim3(32, 32), 256, 0, stream>>>(qkvb, vtb, attno);

    gemm_bt<float><<<dim3(8, 32), 256, 0, stream>>>(attno, woutb, out, 4096, 1024, 1024);
}

// Round 5
// 159.592 us; speedup vs baseline: 2.5245x; 2.5041x over previous
//
#include <hip/hip_runtime.h>

typedef unsigned short u16;
typedef __attribute__((ext_vector_type(8))) short bf16x8;   // 8 bf16 in 4 VGPRs
typedef __attribute__((ext_vector_type(4))) float f32x4;
typedef __attribute__((ext_vector_type(4))) unsigned short u16x4;
typedef __attribute__((ext_vector_type(2))) unsigned short u16x2;

__device__ __forceinline__ u16 f2bf(float f) {
    unsigned int u = __builtin_bit_cast(unsigned int, f);
    u += 0x7fffu + ((u >> 16) & 1u);          // round-to-nearest-even
    return (u16)(u >> 16);
}

__device__ __forceinline__ void gload_lds16(const u16* g, const u16* l) {
    __builtin_amdgcn_global_load_lds((const __attribute__((address_space(1))) void*)g,
                                     (__attribute__((address_space(3))) void*)l,
                                     16, 0, 0);
}

// ---------------- fp32 -> bf16 conversion ----------------
__global__ __launch_bounds__(256) void cvt_f32_bf16(const float* __restrict__ in,
                                                    u16* __restrict__ out, int n4) {
    int i = blockIdx.x * blockDim.x + threadIdx.x;
    int stride = gridDim.x * blockDim.x;
    for (; i < n4; i += stride) {
        float4 v = reinterpret_cast<const float4*>(in)[i];
        u16x4 o = { f2bf(v.x), f2bf(v.y), f2bf(v.z), f2bf(v.w) };
        reinterpret_cast<u16x4*>(out)[i] = o;
    }
}

// ---------------- bf16 GEMM: C[m,n] = sum_k A[m,k] * B[n,k] ----------------
template <typename OutT>
__global__ __launch_bounds__(256) void gemm_bt(const u16* __restrict__ A, const u16* __restrict__ B,
                                               OutT* __restrict__ C, int M, int N, int K) {
    __shared__ u16 ldsA[128 * 64];
    __shared__ u16 ldsB[128 * 64];
    const int tid = threadIdx.x;
    const int lane = tid & 63;
    const int wid = tid >> 6;
    const int wm = wid >> 1, wn = wid & 1;
    const int lq = lane & 15, lg = lane >> 4;
    const int bm = blockIdx.y * 128, bn = blockIdx.x * 128;

    const u16* aSrc[4];
    const u16* bSrc[4];
    int dstOff[4];
#pragma unroll
    for (int j = 0; j < 4; ++j) {
        int item = j * 256 + tid;
        int row = item >> 3;
        int c16 = item & 7;
        aSrc[j] = A + (size_t)(bm + row) * K + c16 * 8;
        bSrc[j] = B + (size_t)(bn + row) * K + c16 * 8;
        dstOff[j] = (j * 256 + (tid & ~63)) * 16;
    }

    f32x4 acc[4][4] = {};
    for (int k0 = 0; k0 < K; k0 += 64) {
        if (k0) __syncthreads();
#pragma unroll
        for (int j = 0; j < 4; ++j) {
            gload_lds16(aSrc[j], (const u16*)((const char*)ldsA + dstOff[j]));
            gload_lds16(bSrc[j], (const u16*)((const char*)ldsB + dstOff[j]));
            aSrc[j] += 64;
            bSrc[j] += 64;
        }
        __syncthreads();
#pragma unroll
        for (int kk = 0; kk < 2; ++kk) {
            bf16x8 af[4], bfr[4];
#pragma unroll
            for (int m = 0; m < 4; ++m) {
                int row = wm * 64 + m * 16 + lq;
                af[m] = *(const bf16x8*)((const char*)ldsA + row * 128 + kk * 64 + lg * 16);
            }
#pragma unroll
            for (int n = 0; n < 4; ++n) {
                int row = wn * 64 + n * 16 + lq;
                bfr[n] = *(const bf16x8*)((const char*)ldsB + row * 128 + kk * 64 + lg * 16);
            }
#pragma unroll
            for (int m = 0; m < 4; ++m)
#pragma unroll
                for (int n = 0; n < 4; ++n)
                    acc[m][n] = __builtin_amdgcn_mfma_f32_16x16x32_bf16(af[m], bfr[n], acc[m][n], 0, 0, 0);
        }
    }

#pragma unroll
    for (int m = 0; m < 4; ++m) {
#pragma unroll
        for (int n = 0; n < 4; ++n) {
#pragma unroll
            for (int r = 0; r < 4; ++r) {
                int row = bm + wm * 64 + m * 16 + lg * 4 + r;
                int col = bn + wn * 64 + n * 16 + lq;
                float v = acc[m][n][r];
                if constexpr (sizeof(OutT) == 2)
                    C[(size_t)row * N + col] = (OutT)f2bf(v);
                else
                    C[(size_t)row * N + col] = (OutT)v;
            }
        }
    }
}

// ---------------- transpose V: (B,T,[v]H,hd) -> (B,H,hd,T) ----------------
__global__ __launch_bounds__(256) void transpose_v(const u16* __restrict__ qkv, u16* __restrict__ vt) {
    __shared__ u16 tile[64][72];
    const int tb = blockIdx.x * 64;
    const int bh = blockIdx.y;
    const int b = bh >> 4, h = bh & 15;
    const u16* src = qkv + ((size_t)(b * 2048 + tb)) * 3072 + 2048 + h * 64;
    const int tid = threadIdx.x;
#pragma unroll
    for (int p = 0; p < 2; ++p) {
        int item = p * 256 + tid;
        int t = item >> 3, c = item & 7;
        bf16x8 v = *(const bf16x8*)(src + (size_t)t * 3072 + c * 8);
        *(bf16x8*)(&tile[t][c * 8]) = v;
    }
    __syncthreads();
    u16* dst = vt + ((size_t)bh * 64) * 2048 + tb;
#pragma unroll
    for (int p = 0; p < 2; ++p) {
        int item = p * 256 + tid;
        int d = item >> 3, tc = item & 7;
        bf16x8 o;
#pragma unroll
        for (int j = 0; j < 8; ++j) o[j] = (short)tile[tc * 8 + j][d];
        *(bf16x8*)(dst + (size_t)d * 2048 + tc * 8) = o;
    }
}

// ---------------- flash attention, causal, hd=64, LDS-staged K/V ----------------
// Block: 4 waves x 32 q-rows = 128-row q tile. KV block = 64.
// K/V staged cooperatively into LDS (double-buffered, XOR-swizzled chunks,
// raw s_barrier + counted vmcnt so prefetch loads stay in flight).
__global__ __launch_bounds__(256) void fhn_attn(const u16* __restrict__ qkv, const u16* __restrict__ vt,
                                                u16* __restrict__ attno) {
    __shared__ u16 kvbuf[2][2][64 * 64];      // [dbuf][0=K,1=V][row][chunk swizzled]  32 KB
    __shared__ u16 plds[4][2][16][72];        // per-wave P tiles (+8 pad)            18 KB
    const int bh = blockIdx.y;
    // load-balance: pair heavy (qt=15-x) with light (qt=x) tiles across bh halves
    const int qt = (bh < 16) ? (15 - (int)blockIdx.x) : (int)blockIdx.x;
    const int b = bh >> 4, h = bh & 15;
    const int tid = threadIdx.x;
    const int w = tid >> 6;
    const int lane = tid & 63;
    const int lq = lane & 15, lg = lane >> 4;
    const int qlo = qt * 128 + w * 32;        // wave's first q row

    // Q fragments: B-operand of swapped QK^T. qf[m][kk] = Q[qlo+m*16+lq][kk*32+lg*8 ..]
    bf16x8 qf[2][2];
#pragma unroll
    for (int m = 0; m < 2; ++m) {
        const u16* qrow = qkv + ((size_t)(b * 2048 + qlo + m * 16 + lq)) * 3072 + h * 64;
        qf[m][0] = *(const bf16x8*)(qrow + lg * 8);
        qf[m][1] = *(const bf16x8*)(qrow + 32 + lg * 8);
    }

    // staging: K tile 64 rows x 8 chunks(16B) = 512 chunks; same for V. 2 chunks/thread each.
    // LDS[row][c] = G[row][c ^ (row&7)]  (pre-swizzled global source, linear LDS dest)
    const int it0 = tid, it1 = 256 + tid;
    const int r0 = it0 >> 3, g0 = (it0 & 7) ^ (r0 & 7);
    const int r1 = it1 >> 3, g1 = (it1 & 7) ^ (r1 & 7);
    const u16* kS0 = qkv + ((size_t)(b * 2048 + r0)) * 3072 + 1024 + h * 64 + g0 * 8;
    const u16* kS1 = qkv + ((size_t)(b * 2048 + r1)) * 3072 + 1024 + h * 64 + g1 * 8;
    const u16* vS0 = vt + ((size_t)bh * 64 + r0) * 2048 + g0 * 8;
    const u16* vS1 = vt + ((size_t)bh * 64 + r1) * 2048 + g1 * 8;
    const int d0 = (it0 & ~63) * 8;           // wave-uniform LDS element base (lane x16B auto)
    const int d1 = (it1 & ~63) * 8;

#define STAGE(buf)                                            \
    do {                                                      \
        gload_lds16(kS0, &kvbuf[buf][0][d0]);                 \
        gload_lds16(kS1, &kvbuf[buf][0][d1]);                 \
        gload_lds16(vS0, &kvbuf[buf][1][d0]);                 \
        gload_lds16(vS1, &kvbuf[buf][1][d1]);                 \
        kS0 += 64 * 3072; kS1 += 64 * 3072;                   \
        vS0 += 64; vS1 += 64;                                 \
    } while (0)

    const int nkv = 2 * qt + 2;
    float m_run[2] = { -1e30f, -1e30f }, l_run[2] = { 0.f, 0.f };
    f32x4 oacc[2][4] = {};
    int cur = 0;

    STAGE(0);                                  // prefetch jb=0

    for (int jb = 0; jb < nkv; ++jb) {
        const int sb = jb * 64;
        if (jb + 1 < nkv) {
            STAGE(cur ^ 1);                    // 4 more loads in flight
            asm volatile("s_waitcnt vmcnt(4)" ::: "memory");   // wait only current tile
        } else {
            asm volatile("s_waitcnt vmcnt(0)" ::: "memory");
        }
        __builtin_amdgcn_s_barrier();
        __builtin_amdgcn_sched_barrier(0);

        const u16* kb = kvbuf[cur][0];
        const u16* vb = kvbuf[cur][1];

        if (sb <= qlo + 31) {                  // wave has unmasked work in this kv block
            const bool dodiag = (sb + 63 > qlo);

            // K fragments (A-operand), shared by both q-subtiles
            bf16x8 kf[4][2];
#pragma unroll
            for (int st = 0; st < 4; ++st) {
                int row = st * 16 + lq;
#pragma unroll
                for (int kk = 0; kk < 2; ++kk)
                    kf[st][kk] = *(const bf16x8*)(kb + row * 64 + (((kk * 4 + lg) ^ (row & 7)) * 8));
            }

#pragma unroll
            for (int m = 0; m < 2; ++m) {
                const int tq = qlo + m * 16 + lq;      // softmax row owned by this lane
                float p[4][4];
                float mloc = -1e30f;
#pragma unroll
                for (int st = 0; st < 4; ++st) {
                    f32x4 sacc = {};
                    sacc = __builtin_amdgcn_mfma_f32_16x16x32_bf16(kf[st][0], qf[m][0], sacc, 0, 0, 0);
                    sacc = __builtin_amdgcn_mfma_f32_16x16x32_bf16(kf[st][1], qf[m][1], sacc, 0, 0, 0);
#pragma unroll
                    for (int r = 0; r < 4; ++r) {
                        int s = sb + st * 16 + lg * 4 + r;
                        float sc = sacc[r] * 0.1803368801f;   // (1/sqrt(64)) * log2(e)
                        if (dodiag && s > tq) sc = -1e30f;
                        p[st][r] = sc;
                        mloc = fmaxf(mloc, sc);
                    }
                }
                mloc = fmaxf(mloc, __shfl_xor(mloc, 16));
                mloc = fmaxf(mloc, __shfl_xor(mloc, 32));
                float mnew = fmaxf(m_run[m], mloc);
                float scp = exp2f(m_run[m] - mnew);

                float lloc = 0.f;
#pragma unroll
                for (int st = 0; st < 4; ++st)
#pragma unroll
                    for (int r = 0; r < 4; ++r) {
                        float e = exp2f(p[st][r] - mnew);
                        p[st][r] = e;
                        lloc += e;
                    }
                lloc += __shfl_xor(lloc, 16);
                lloc += __shfl_xor(lloc, 32);
                l_run[m] = l_run[m] * scp + lloc;
                m_run[m] = mnew;

                // P^T -> plds as P[q][s] (bf16)
#pragma unroll
                for (int st = 0; st < 4; ++st)
#pragma unroll
                    for (int rp = 0; rp < 2; ++rp) {
                        u16x2 pk = { f2bf(p[st][2 * rp]), f2bf(p[st][2 * rp + 1]) };
                        *(u16x2*)(&plds[w][m][lq][st * 16 + lg * 4 + 2 * rp]) = pk;
                    }

                // rescale running O for this subtile (output rows q = lg*4+r)
                float f0 = __shfl(scp, lg * 4 + 0);
                float f1 = __shfl(scp, lg * 4 + 1);
                float f2_ = __shfl(scp, lg * 4 + 2);
                float f3 = __shfl(scp, lg * 4 + 3);
#pragma unroll
                for (int nd = 0; nd < 4; ++nd) {
                    oacc[m][nd][0] *= f0; oacc[m][nd][1] *= f1;
                    oacc[m][nd][2] *= f2_; oacc[m][nd][3] *= f3;
                }
            }

            // V fragments (B-operand), shared by both q-subtiles
            bf16x8 vf[2][4];
#pragma unroll
            for (int c = 0; c < 2; ++c)
#pragma unroll
                for (int nd = 0; nd < 4; ++nd) {
                    int row = nd * 16 + lq;
                    vf[c][nd] = *(const bf16x8*)(vb + row * 64 + (((c * 4 + lg) ^ (row & 7)) * 8));
                }

#pragma unroll
            for (int m = 0; m < 2; ++m)
#pragma unroll
                for (int c = 0; c < 2; ++c) {
                    bf16x8 pa = *(const bf16x8*)(&plds[w][m][lq][c * 32 + lg * 8]);
#pragma unroll
                    for (int nd = 0; nd < 4; ++nd)
                        oacc[m][nd] = __builtin_amdgcn_mfma_f32_16x16x32_bf16(pa, vf[c][nd], oacc[m][nd], 0, 0, 0);
                }
        }

        __builtin_amdgcn_sched_barrier(0);
        __builtin_amdgcn_s_barrier();          // all reads of buf done before next overwrite
        cur ^= 1;
    }
#undef STAGE

    // epilogue: divide by l, store bf16 (B,T,H*hd)
#pragma unroll
    for (int m = 0; m < 2; ++m) {
        float li0 = 1.f / __shfl(l_run[m], lg * 4 + 0);
        float li1 = 1.f / __shfl(l_run[m], lg * 4 + 1);
        float li2 = 1.f / __shfl(l_run[m], lg * 4 + 2);
        float li3 = 1.f / __shfl(l_run[m], lg * 4 + 3);
#pragma unroll
        for (int nd = 0; nd < 4; ++nd) {
#pragma unroll
            for (int r = 0; r < 4; ++r) {
                int trow = qlo + m * 16 + lg * 4 + r;
                float li = (r == 0) ? li0 : (r == 1) ? li1 : (r == 2) ? li2 : li3;
                attno[((size_t)(b * 2048 + trow)) * 1024 + h * 64 + nd * 16 + lq] =
                    f2bf(oacc[m][nd][r] * li);
            }
        }
    }
}

extern "C" void kernel_launch(void* const* d_in, const int* in_sizes, int n_in,
                              void* d_out, int out_size, void* d_ws, size_t ws_size,
                              hipStream_t stream) {
    const float* x    = (const float*)d_in[0];   // (2,2048,1024)
    const float* Wqkv = (const float*)d_in[1];   // (3072,1024)
    const float* Wout = (const float*)d_in[2];   // (1024,1024)
    float* out = (float*)d_out;

    char* ws = (char*)d_ws;
    u16* xb    = (u16*)(ws + 0);           //  8,388,608 B
    u16* wqkvb = (u16*)(ws + 8388608);     //  6,291,456 B
    u16* woutb = (u16*)(ws + 14680064);    //  2,097,152 B
    u16* qkvb  = (u16*)(ws + 16777216);    // 25,165,824 B
    u16* vtb   = (u16*)(ws + 41943040);    //  8,388,608 B
    u16* attno = (u16*)(ws + 50331648);    //  8,388,608 B  (end 58,720,256)

    cvt_f32_bf16<<<2048, 256, 0, stream>>>(x, xb, 4194304 / 4);
    cvt_f32_bf16<<<2048, 256, 0, stream>>>(Wqkv, wqkvb, 3145728 / 4);
    cvt_f32_bf16<<<1024, 256, 0, stream>>>(Wout, woutb, 1048576 / 4);

    gemm_bt<u16><<<dim3(24, 32), 256, 0, stream>>>(xb, wqkvb, qkvb, 4096, 3072, 1024);

    transpose_v<<<dim3(32, 32), 256, 0, stream>>>(qkvb, vtb);

    fhn_attn<<<dim3(16, 32), 256, 0, stream>>>(qkvb, vtb, attno);

    gemm_bt<float><<<dim3(8, 32), 256, 0, stream>>>(attno, woutb, out, 4096, 1024, 1024);
}

// Round 6
// 132.150 us; speedup vs baseline: 3.0487x; 1.2077x over previous
//
#include <hip/hip_runtime.h>

typedef unsigned short u16;
typedef __attribute__((ext_vector_type(8))) short bf16x8;   // 8 bf16 in 4 VGPRs
typedef __attribute__((ext_vector_type(4))) float f32x4;
typedef __attribute__((ext_vector_type(4))) unsigned short u16x4;
typedef __attribute__((ext_vector_type(2))) unsigned short u16x2;

__device__ __forceinline__ u16 f2bf(float f) {
    unsigned int u = __builtin_bit_cast(unsigned int, f);
    u += 0x7fffu + ((u >> 16) & 1u);          // round-to-nearest-even
    return (u16)(u >> 16);
}

__device__ __forceinline__ float bf2f(u16 b) {
    unsigned int u = ((unsigned int)b) << 16;
    return __builtin_bit_cast(float, u);
}

__device__ __forceinline__ void gload_lds16(const u16* g, const u16* l) {
    __builtin_amdgcn_global_load_lds((const __attribute__((address_space(1))) void*)g,
                                     (__attribute__((address_space(3))) void*)l,
                                     16, 0, 0);
}

// ---------------- fp32 -> bf16 conversion ----------------
__global__ __launch_bounds__(256) void cvt_f32_bf16(const float* __restrict__ in,
                                                    u16* __restrict__ out, int n4) {
    int i = blockIdx.x * blockDim.x + threadIdx.x;
    int stride = gridDim.x * blockDim.x;
    for (; i < n4; i += stride) {
        float4 v = reinterpret_cast<const float4*>(in)[i];
        u16x4 o = { f2bf(v.x), f2bf(v.y), f2bf(v.z), f2bf(v.w) };
        reinterpret_cast<u16x4*>(out)[i] = o;
    }
}

// ---------------- bf16 GEMM: C[m,n] = sum_k A[m,k] * B[n,k] ----------------
template <typename OutT>
__global__ __launch_bounds__(256) void gemm_bt(const u16* __restrict__ A, const u16* __restrict__ B,
                                               OutT* __restrict__ C, int M, int N, int K) {
    __shared__ u16 ldsA[128 * 64];
    __shared__ u16 ldsB[128 * 64];
    const int tid = threadIdx.x;
    const int lane = tid & 63;
    const int wid = tid >> 6;
    const int wm = wid >> 1, wn = wid & 1;
    const int lq = lane & 15, lg = lane >> 4;
    const int bm = blockIdx.y * 128, bn = blockIdx.x * 128;

    const u16* aSrc[4];
    const u16* bSrc[4];
    int dstOff[4];
#pragma unroll
    for (int j = 0; j < 4; ++j) {
        int item = j * 256 + tid;
        int row = item >> 3;
        int c16 = item & 7;
        aSrc[j] = A + (size_t)(bm + row) * K + c16 * 8;
        bSrc[j] = B + (size_t)(bn + row) * K + c16 * 8;
        dstOff[j] = (j * 256 + (tid & ~63)) * 16;
    }

    f32x4 acc[4][4] = {};
    for (int k0 = 0; k0 < K; k0 += 64) {
        if (k0) __syncthreads();
#pragma unroll
        for (int j = 0; j < 4; ++j) {
            gload_lds16(aSrc[j], (const u16*)((const char*)ldsA + dstOff[j]));
            gload_lds16(bSrc[j], (const u16*)((const char*)ldsB + dstOff[j]));
            aSrc[j] += 64;
            bSrc[j] += 64;
        }
        __syncthreads();
#pragma unroll
        for (int kk = 0; kk < 2; ++kk) {
            bf16x8 af[4], bfr[4];
#pragma unroll
            for (int m = 0; m < 4; ++m) {
                int row = wm * 64 + m * 16 + lq;
                af[m] = *(const bf16x8*)((const char*)ldsA + row * 128 + kk * 64 + lg * 16);
            }
#pragma unroll
            for (int n = 0; n < 4; ++n) {
                int row = wn * 64 + n * 16 + lq;
                bfr[n] = *(const bf16x8*)((const char*)ldsB + row * 128 + kk * 64 + lg * 16);
            }
#pragma unroll
            for (int m = 0; m < 4; ++m)
#pragma unroll
                for (int n = 0; n < 4; ++n)
                    acc[m][n] = __builtin_amdgcn_mfma_f32_16x16x32_bf16(af[m], bfr[n], acc[m][n], 0, 0, 0);
        }
    }

#pragma unroll
    for (int m = 0; m < 4; ++m) {
#pragma unroll
        for (int n = 0; n < 4; ++n) {
#pragma unroll
            for (int r = 0; r < 4; ++r) {
                int row = bm + wm * 64 + m * 16 + lg * 4 + r;
                int col = bn + wn * 64 + n * 16 + lq;
                float v = acc[m][n][r];
                if constexpr (sizeof(OutT) == 2)
                    C[(size_t)row * N + col] = (OutT)f2bf(v);
                else
                    C[(size_t)row * N + col] = (OutT)v;
            }
        }
    }
}

// ---------------- transpose V: (B,T,[v]H,hd) -> (B,H,hd,T) ----------------
__global__ __launch_bounds__(256) void transpose_v(const u16* __restrict__ qkv, u16* __restrict__ vt) {
    __shared__ u16 tile[64][72];
    const int tb = blockIdx.x * 64;
    const int bh = blockIdx.y;
    const int b = bh >> 4, h = bh & 15;
    const u16* src = qkv + ((size_t)(b * 2048 + tb)) * 3072 + 2048 + h * 64;
    const int tid = threadIdx.x;
#pragma unroll
    for (int p = 0; p < 2; ++p) {
        int item = p * 256 + tid;
        int t = item >> 3, c = item & 7;
        bf16x8 v = *(const bf16x8*)(src + (size_t)t * 3072 + c * 8);
        *(bf16x8*)(&tile[t][c * 8]) = v;
    }
    __syncthreads();
    u16* dst = vt + ((size_t)bh * 64) * 2048 + tb;
#pragma unroll
    for (int p = 0; p < 2; ++p) {
        int item = p * 256 + tid;
        int d = item >> 3, tc = item & 7;
        bf16x8 o;
#pragma unroll
        for (int j = 0; j < 8; ++j) o[j] = (short)tile[tc * 8 + j][d];
        *(bf16x8*)(dst + (size_t)d * 2048 + tc * 8) = o;
    }
}

// ---------------- flash attention, causal, hd=64, LDS-staged K/V ----------------
// Block: 4 waves x 16 q-rows = 64-row q tile; grid 32x32 = 1024 blocks -> 4/CU.
// LDS exactly 40 KB (kvbuf 32K dbuf + plds 8K XOR-swizzled, no pad) so 4 blocks fit.
// Double-buffered K/V staging via global_load_lds, raw s_barrier + counted vmcnt.
__global__ __launch_bounds__(256, 4) void fhn_attn(const u16* __restrict__ qkv, const u16* __restrict__ vt,
                                                   u16* __restrict__ attno) {
    __shared__ u16 kvbuf[2][2][64 * 64];      // [dbuf][0=K,1=V][row][chunk swizzled]  32 KB
    __shared__ u16 plds[4][16][64];           // per-wave P tile, XOR-swizzled          8 KB
    const int bh = blockIdx.y;
    // load-balance: pair heavy with light q-tiles across bh halves
    const int qt = (bh < 16) ? (31 - (int)blockIdx.x) : (int)blockIdx.x;
    const int b = bh >> 4, h = bh & 15;
    const int tid = threadIdx.x;
    const int w = tid >> 6;
    const int lane = tid & 63;
    const int lq = lane & 15, lg = lane >> 4;
    const int qlo = qt * 64 + w * 16;         // wave's first q row
    const int tq = qlo + lq;                  // softmax row owned by this lane

    // Q fragments (B-operand of swapped QK^T), pre-scaled by log2(e)/sqrt(64)
    bf16x8 qf[2];
    {
        const u16* qrow = qkv + ((size_t)(b * 2048 + tq)) * 3072 + h * 64;
        qf[0] = *(const bf16x8*)(qrow + lg * 8);
        qf[1] = *(const bf16x8*)(qrow + 32 + lg * 8);
#pragma unroll
        for (int kk = 0; kk < 2; ++kk)
#pragma unroll
            for (int j = 0; j < 8; ++j)
                qf[kk][j] = (short)f2bf(bf2f((u16)qf[kk][j]) * 0.1803368801f);
    }

    // staging: 64 rows x 8 chunks(16B) per tile; 2 chunks/thread for K and V each.
    // LDS[row][c] = G[row][c ^ (row&7)]  (pre-swizzled global source, linear LDS dest)
    const int it0 = tid, it1 = 256 + tid;
    const int r0 = it0 >> 3, g0 = (it0 & 7) ^ (r0 & 7);
    const int r1 = it1 >> 3, g1 = (it1 & 7) ^ (r1 & 7);
    const u16* kS0 = qkv + ((size_t)(b * 2048 + r0)) * 3072 + 1024 + h * 64 + g0 * 8;
    const u16* kS1 = qkv + ((size_t)(b * 2048 + r1)) * 3072 + 1024 + h * 64 + g1 * 8;
    const u16* vS0 = vt + ((size_t)bh * 64 + r0) * 2048 + g0 * 8;
    const u16* vS1 = vt + ((size_t)bh * 64 + r1) * 2048 + g1 * 8;
    const int d0 = (it0 & ~63) * 8;           // wave-uniform LDS element base
    const int d1 = (it1 & ~63) * 8;

#define STAGE(buf)                                            \
    do {                                                      \
        gload_lds16(kS0, &kvbuf[buf][0][d0]);                 \
        gload_lds16(kS1, &kvbuf[buf][0][d1]);                 \
        gload_lds16(vS0, &kvbuf[buf][1][d0]);                 \
        gload_lds16(vS1, &kvbuf[buf][1][d1]);                 \
        kS0 += 64 * 3072; kS1 += 64 * 3072;                   \
        vS0 += 64; vS1 += 64;                                 \
    } while (0)

    const int nkv = qt + 1;
    float m_run = -1e30f, l_run = 0.f;
    f32x4 oacc[4] = {};
    int cur = 0;

    char* const pbase = (char*)&plds[w][0][0] + lq * 128;
    const int pswz = (lq & 7) << 4;

    STAGE(0);                                  // prefetch jb=0

    for (int jb = 0; jb < nkv; ++jb) {
        if (jb + 1 < nkv) {
            STAGE(cur ^ 1);                    // next tile's 4 loads stay in flight
            asm volatile("s_waitcnt vmcnt(4)" ::: "memory");   // current tile ready
        } else {
            asm volatile("s_waitcnt vmcnt(0)" ::: "memory");
        }
        __builtin_amdgcn_s_barrier();
        __builtin_amdgcn_sched_barrier(0);

        const u16* kb = kvbuf[cur][0];
        const u16* vb = kvbuf[cur][1];

        // ---- QK^T (swapped): S^T = K * Q^T, scores already in log2 units
        float p[4][4];
#pragma unroll
        for (int st = 0; st < 4; ++st) {
            int row = st * 16 + lq;
            f32x4 sacc = {};
            sacc = __builtin_amdgcn_mfma_f32_16x16x32_bf16(
                *(const bf16x8*)(kb + row * 64 + ((lg ^ (row & 7)) * 8)), qf[0], sacc, 0, 0, 0);
            sacc = __builtin_amdgcn_mfma_f32_16x16x32_bf16(
                *(const bf16x8*)(kb + row * 64 + (((4 + lg) ^ (row & 7)) * 8)), qf[1], sacc, 0, 0, 0);
#pragma unroll
            for (int r = 0; r < 4; ++r) p[st][r] = sacc[r];
        }

        if (jb == qt) {                        // block-uniform: mask only diagonal tile
#pragma unroll
            for (int st = 0; st < 4; ++st)
#pragma unroll
                for (int r = 0; r < 4; ++r) {
                    int s = jb * 64 + st * 16 + lg * 4 + r;
                    if (s > tq) p[st][r] = -1e30f;
                }
        }

        float mloc = p[0][0];
#pragma unroll
        for (int st = 0; st < 4; ++st)
#pragma unroll
            for (int r = 0; r < 4; ++r) mloc = fmaxf(mloc, p[st][r]);
        mloc = fmaxf(mloc, __shfl_xor(mloc, 16));
        mloc = fmaxf(mloc, __shfl_xor(mloc, 32));

        // defer-max: skip O-rescale while row max grows by <= 8 (log2 domain)
        if (!__all(mloc - m_run <= 8.0f)) {
            float mnew = fmaxf(m_run, mloc);
            float scp = exp2f(m_run - mnew);
            m_run = mnew;
            l_run *= scp;
            float f0 = __shfl(scp, lg * 4 + 0);
            float f1 = __shfl(scp, lg * 4 + 1);
            float f2_ = __shfl(scp, lg * 4 + 2);
            float f3 = __shfl(scp, lg * 4 + 3);
#pragma unroll
            for (int nd = 0; nd < 4; ++nd) {
                oacc[nd][0] *= f0; oacc[nd][1] *= f1;
                oacc[nd][2] *= f2_; oacc[nd][3] *= f3;
            }
        }

        float lloc = 0.f;
#pragma unroll
        for (int st = 0; st < 4; ++st)
#pragma unroll
            for (int r = 0; r < 4; ++r) {
                float e = exp2f(p[st][r] - m_run);
                p[st][r] = e;
                lloc += e;
            }
        lloc += __shfl_xor(lloc, 16);
        lloc += __shfl_xor(lloc, 32);
        l_run += lloc;

        // P^T -> plds as P[q][s] (bf16, swizzled row)
#pragma unroll
        for (int st = 0; st < 4; ++st) {
            u16x4 pk = { f2bf(p[st][0]), f2bf(p[st][1]), f2bf(p[st][2]), f2bf(p[st][3]) };
            *(u16x4*)(pbase + ((st * 32 + lg * 8) ^ pswz)) = pk;
        }

        // ---- PV: O += P * V
#pragma unroll
        for (int c = 0; c < 2; ++c) {
            bf16x8 pa = *(const bf16x8*)(pbase + ((c * 64 + lg * 16) ^ pswz));
#pragma unroll
            for (int nd = 0; nd < 4; ++nd) {
                int row = nd * 16 + lq;
                bf16x8 vf = *(const bf16x8*)(vb + row * 64 + (((c * 4 + lg) ^ (row & 7)) * 8));
                oacc[nd] = __builtin_amdgcn_mfma_f32_16x16x32_bf16(pa, vf, oacc[nd], 0, 0, 0);
            }
        }

        __builtin_amdgcn_sched_barrier(0);
        __builtin_amdgcn_s_barrier();          // all reads of buf done before overwrite
        cur ^= 1;
    }
#undef STAGE

    // epilogue: divide by l (per output row q = lg*4+r), store bf16 (B,T,H*hd)
    float li0 = 1.f / __shfl(l_run, lg * 4 + 0);
    float li1 = 1.f / __shfl(l_run, lg * 4 + 1);
    float li2 = 1.f / __shfl(l_run, lg * 4 + 2);
    float li3 = 1.f / __shfl(l_run, lg * 4 + 3);
#pragma unroll
    for (int nd = 0; nd < 4; ++nd) {
#pragma unroll
        for (int r = 0; r < 4; ++r) {
            int trow = qlo + lg * 4 + r;
            float li = (r == 0) ? li0 : (r == 1) ? li1 : (r == 2) ? li2 : li3;
            attno[((size_t)(b * 2048 + trow)) * 1024 + h * 64 + nd * 16 + lq] =
                f2bf(oacc[nd][r] * li);
        }
    }
}

extern "C" void kernel_launch(void* const* d_in, const int* in_sizes, int n_in,
                              void* d_out, int out_size, void* d_ws, size_t ws_size,
                              hipStream_t stream) {
    const float* x    = (const float*)d_in[0];   // (2,2048,1024)
    const float* Wqkv = (const float*)d_in[1];   // (3072,1024)
    const float* Wout = (const float*)d_in[2];   // (1024,1024)
    float* out = (float*)d_out;

    char* ws = (char*)d_ws;
    u16* xb    = (u16*)(ws + 0);           //  8,388,608 B
    u16* wqkvb = (u16*)(ws + 8388608);     //  6,291,456 B
    u16* woutb = (u16*)(ws + 14680064);    //  2,097,152 B
    u16* qkvb  = (u16*)(ws + 16777216);    // 25,165,824 B
    u16* vtb   = (u16*)(ws + 41943040);    //  8,388,608 B
    u16* attno = (u16*)(ws + 50331648);    //  8,388,608 B  (end 58,720,256)

    cvt_f32_bf16<<<2048, 256, 0, stream>>>(x, xb, 4194304 / 4);
    cvt_f32_bf16<<<2048, 256, 0, stream>>>(Wqkv, wqkvb, 3145728 / 4);
    cvt_f32_bf16<<<1024, 256, 0, stream>>>(Wout, woutb, 1048576 / 4);

    gemm_bt<u16><<<dim3(24, 32), 256, 0, stream>>>(xb, wqkvb, qkvb, 4096, 3072, 1024);

    transpose_v<<<dim3(32, 32), 256, 0, stream>>>(qkvb, vtb);

    fhn_attn<<<dim3(32, 32), 256, 0, stream>>>(qkvb, vtb, attno);

    gemm_bt<float><<<dim3(8, 32), 256, 0, stream>>>(attno, woutb, out, 4096, 1024, 1024);
}

// Round 7
// 131.845 us; speedup vs baseline: 3.0558x; 1.0023x over previous
//
#include <hip/hip_runtime.h>

typedef unsigned short u16;
typedef __attribute__((ext_vector_type(8))) short bf16x8;   // 8 bf16 in 4 VGPRs
typedef __attribute__((ext_vector_type(4))) float f32x4;
typedef __attribute__((ext_vector_type(4))) unsigned short u16x4;
typedef __attribute__((ext_vector_type(2))) unsigned int u32x2;

__device__ __forceinline__ u16 f2bf(float f) {
    unsigned int u = __builtin_bit_cast(unsigned int, f);
    u += 0x7fffu + ((u >> 16) & 1u);          // round-to-nearest-even
    return (u16)(u >> 16);
}

__device__ __forceinline__ float bf2f(u16 b) {
    unsigned int u = ((unsigned int)b) << 16;
    return __builtin_bit_cast(float, u);
}

__device__ __forceinline__ unsigned int cvt_pk_bf16(float lo, float hi) {
    unsigned int r;
    asm("v_cvt_pk_bf16_f32 %0, %1, %2" : "=v"(r) : "v"(lo), "v"(hi));
    return r;                                  // [15:0]=bf16(lo) [31:16]=bf16(hi)
}

__device__ __forceinline__ void gload_lds16(const u16* g, const u16* l) {
    __builtin_amdgcn_global_load_lds((const __attribute__((address_space(1))) void*)g,
                                     (__attribute__((address_space(3))) void*)l,
                                     16, 0, 0);
}

// ---------------- fp32 -> bf16 conversion ----------------
__global__ __launch_bounds__(256) void cvt_f32_bf16(const float* __restrict__ in,
                                                    u16* __restrict__ out, int n4) {
    int i = blockIdx.x * blockDim.x + threadIdx.x;
    int stride = gridDim.x * blockDim.x;
    for (; i < n4; i += stride) {
        float4 v = reinterpret_cast<const float4*>(in)[i];
        u16x4 o = { f2bf(v.x), f2bf(v.y), f2bf(v.z), f2bf(v.w) };
        reinterpret_cast<u16x4*>(out)[i] = o;
    }
}

// ---------------- bf16 GEMM: C[m,n] = sum_k A[m,k] * B[n,k] ----------------
template <typename OutT>
__global__ __launch_bounds__(256) void gemm_bt(const u16* __restrict__ A, const u16* __restrict__ B,
                                               OutT* __restrict__ C, int M, int N, int K) {
    __shared__ u16 ldsA[128 * 64];
    __shared__ u16 ldsB[128 * 64];
    const int tid = threadIdx.x;
    const int lane = tid & 63;
    const int wid = tid >> 6;
    const int wm = wid >> 1, wn = wid & 1;
    const int lq = lane & 15, lg = lane >> 4;
    const int bm = blockIdx.y * 128, bn = blockIdx.x * 128;

    const u16* aSrc[4];
    const u16* bSrc[4];
    int dstOff[4];
#pragma unroll
    for (int j = 0; j < 4; ++j) {
        int item = j * 256 + tid;
        int row = item >> 3;
        int c16 = item & 7;
        aSrc[j] = A + (size_t)(bm + row) * K + c16 * 8;
        bSrc[j] = B + (size_t)(bn + row) * K + c16 * 8;
        dstOff[j] = (j * 256 + (tid & ~63)) * 16;
    }

    f32x4 acc[4][4] = {};
    for (int k0 = 0; k0 < K; k0 += 64) {
        if (k0) __syncthreads();
#pragma unroll
        for (int j = 0; j < 4; ++j) {
            gload_lds16(aSrc[j], (const u16*)((const char*)ldsA + dstOff[j]));
            gload_lds16(bSrc[j], (const u16*)((const char*)ldsB + dstOff[j]));
            aSrc[j] += 64;
            bSrc[j] += 64;
        }
        __syncthreads();
#pragma unroll
        for (int kk = 0; kk < 2; ++kk) {
            bf16x8 af[4], bfr[4];
#pragma unroll
            for (int m = 0; m < 4; ++m) {
                int row = wm * 64 + m * 16 + lq;
                af[m] = *(const bf16x8*)((const char*)ldsA + row * 128 + kk * 64 + lg * 16);
            }
#pragma unroll
            for (int n = 0; n < 4; ++n) {
                int row = wn * 64 + n * 16 + lq;
                bfr[n] = *(const bf16x8*)((const char*)ldsB + row * 128 + kk * 64 + lg * 16);
            }
#pragma unroll
            for (int m = 0; m < 4; ++m)
#pragma unroll
                for (int n = 0; n < 4; ++n)
                    acc[m][n] = __builtin_amdgcn_mfma_f32_16x16x32_bf16(af[m], bfr[n], acc[m][n], 0, 0, 0);
        }
    }

#pragma unroll
    for (int m = 0; m < 4; ++m) {
#pragma unroll
        for (int n = 0; n < 4; ++n) {
#pragma unroll
            for (int r = 0; r < 4; ++r) {
                int row = bm + wm * 64 + m * 16 + lg * 4 + r;
                int col = bn + wn * 64 + n * 16 + lq;
                float v = acc[m][n][r];
                if constexpr (sizeof(OutT) == 2)
                    C[(size_t)row * N + col] = (OutT)f2bf(v);
                else
                    C[(size_t)row * N + col] = (OutT)v;
            }
        }
    }
}

// ---------------- transpose V: (B,T,[v]H,hd) -> (B,H,hd,T) ----------------
__global__ __launch_bounds__(256) void transpose_v(const u16* __restrict__ qkv, u16* __restrict__ vt) {
    __shared__ u16 tile[64][72];
    const int tb = blockIdx.x * 64;
    const int bh = blockIdx.y;
    const int b = bh >> 4, h = bh & 15;
    const u16* src = qkv + ((size_t)(b * 2048 + tb)) * 3072 + 2048 + h * 64;
    const int tid = threadIdx.x;
#pragma unroll
    for (int p = 0; p < 2; ++p) {
        int item = p * 256 + tid;
        int t = item >> 3, c = item & 7;
        bf16x8 v = *(const bf16x8*)(src + (size_t)t * 3072 + c * 8);
        *(bf16x8*)(&tile[t][c * 8]) = v;
    }
    __syncthreads();
    u16* dst = vt + ((size_t)bh * 64) * 2048 + tb;
#pragma unroll
    for (int p = 0; p < 2; ++p) {
        int item = p * 256 + tid;
        int d = item >> 3, tc = item & 7;
        bf16x8 o;
#pragma unroll
        for (int j = 0; j < 8; ++j) o[j] = (short)tile[tc * 8 + j][d];
        *(bf16x8*)(dst + (size_t)d * 2048 + tc * 8) = o;
    }
}

// ---------------- flash attention, causal, hd=64, LDS-staged K/V ----------------
// 1D grid 1024; bh -> XCD (bh>>2) so each XCD's L2 holds its 4 heads' K/V (2 MB).
// Block: 4 waves x 16 q-rows = 64-row q tile; LDS 40 KB -> 4 blocks/CU resident.
// Double-buffered K/V staging via global_load_lds, raw s_barrier + counted vmcnt.
__global__ __launch_bounds__(256, 4) void fhn_attn(const u16* __restrict__ qkv, const u16* __restrict__ vt,
                                                   u16* __restrict__ attno) {
    __shared__ u16 kvbuf[2][2][64 * 64];      // [dbuf][0=K,1=V][row][chunk swizzled]  32 KB
    __shared__ u16 plds[4][16][64];           // per-wave P tile, XOR-swizzled          8 KB
    // id%8 = XCD; give XCD x the 4 heads bh = x*4..x*4+3; tile = id>>5.
    const int id = blockIdx.x;
    const int bh = (id & 7) * 4 + ((id >> 3) & 3);
    const int tile = id >> 5;
    const int qt = (bh & 1) ? tile : (31 - tile);   // alternate ordering for balance
    const int b = bh >> 4, h = bh & 15;
    const int tid = threadIdx.x;
    const int w = tid >> 6;
    const int lane = tid & 63;
    const int lq = lane & 15, lg = lane >> 4;
    const int qlo = qt * 64 + w * 16;         // wave's first q row
    const int tq = qlo + lq;                  // softmax row owned by this lane

    // Q fragments (B-operand of swapped QK^T), pre-scaled by log2(e)/sqrt(64)
    bf16x8 qf[2];
    {
        const u16* qrow = qkv + ((size_t)(b * 2048 + tq)) * 3072 + h * 64;
        qf[0] = *(const bf16x8*)(qrow + lg * 8);
        qf[1] = *(const bf16x8*)(qrow + 32 + lg * 8);
#pragma unroll
        for (int kk = 0; kk < 2; ++kk)
#pragma unroll
            for (int j = 0; j < 8; ++j)
                qf[kk][j] = (short)f2bf(bf2f((u16)qf[kk][j]) * 0.1803368801f);
    }

    // staging: 64 rows x 8 chunks(16B) per tile; 2 chunks/thread for K and V each.
    // LDS[row][c] = G[row][c ^ (row&7)]  (pre-swizzled global source, linear LDS dest)
    const int it0 = tid, it1 = 256 + tid;
    const int r0 = it0 >> 3, g0 = (it0 & 7) ^ (r0 & 7);
    const int r1 = it1 >> 3, g1 = (it1 & 7) ^ (r1 & 7);
    const u16* kS0 = qkv + ((size_t)(b * 2048 + r0)) * 3072 + 1024 + h * 64 + g0 * 8;
    const u16* kS1 = qkv + ((size_t)(b * 2048 + r1)) * 3072 + 1024 + h * 64 + g1 * 8;
    const u16* vS0 = vt + ((size_t)bh * 64 + r0) * 2048 + g0 * 8;
    const u16* vS1 = vt + ((size_t)bh * 64 + r1) * 2048 + g1 * 8;
    const int d0 = (it0 & ~63) * 8;           // wave-uniform LDS element base
    const int d1 = (it1 & ~63) * 8;

#define STAGE(buf)                                            \
    do {                                                      \
        gload_lds16(kS0, &kvbuf[buf][0][d0]);                 \
        gload_lds16(kS1, &kvbuf[buf][0][d1]);                 \
        gload_lds16(vS0, &kvbuf[buf][1][d0]);                 \
        gload_lds16(vS1, &kvbuf[buf][1][d1]);                 \
        kS0 += 64 * 3072; kS1 += 64 * 3072;                   \
        vS0 += 64; vS1 += 64;                                 \
    } while (0)

    const int nkv = qt + 1;
    float m_run = -1e30f, l_run = 0.f;
    f32x4 oacc[4] = {};
    int cur = 0;

    char* const pbase = (char*)&plds[w][0][0] + lq * 128;
    const int pswz = (lq & 7) << 4;

    STAGE(0);                                  // prefetch jb=0

    for (int jb = 0; jb < nkv; ++jb) {
        if (jb + 1 < nkv) {
            STAGE(cur ^ 1);                    // next tile's 4 loads stay in flight
            asm volatile("s_waitcnt vmcnt(4)" ::: "memory");   // current tile ready
        } else {
            asm volatile("s_waitcnt vmcnt(0)" ::: "memory");
        }
        __builtin_amdgcn_s_barrier();
        __builtin_amdgcn_sched_barrier(0);

        const u16* kb = kvbuf[cur][0];
        const u16* vb = kvbuf[cur][1];

        // ---- QK^T (swapped): S^T = K * Q^T, scores already in log2 units
        float p[4][4];
        __builtin_amdgcn_s_setprio(1);
#pragma unroll
        for (int st = 0; st < 4; ++st) {
            int row = st * 16 + lq;
            f32x4 sacc = {};
            sacc = __builtin_amdgcn_mfma_f32_16x16x32_bf16(
                *(const bf16x8*)(kb + row * 64 + ((lg ^ (row & 7)) * 8)), qf[0], sacc, 0, 0, 0);
            sacc = __builtin_amdgcn_mfma_f32_16x16x32_bf16(
                *(const bf16x8*)(kb + row * 64 + (((4 + lg) ^ (row & 7)) * 8)), qf[1], sacc, 0, 0, 0);
#pragma unroll
            for (int r = 0; r < 4; ++r) p[st][r] = sacc[r];
        }
        __builtin_amdgcn_s_setprio(0);

        if (jb == qt) {                        // block-uniform: mask only diagonal tile
#pragma unroll
            for (int st = 0; st < 4; ++st)
#pragma unroll
                for (int r = 0; r < 4; ++r) {
                    int s = jb * 64 + st * 16 + lg * 4 + r;
                    if (s > tq) p[st][r] = -1e30f;
                }
        }

        // tree max (depth 4 instead of 16-deep serial chain)
        float mst[4];
#pragma unroll
        for (int st = 0; st < 4; ++st)
            mst[st] = fmaxf(fmaxf(p[st][0], p[st][1]), fmaxf(p[st][2], p[st][3]));
        float mloc = fmaxf(fmaxf(mst[0], mst[1]), fmaxf(mst[2], mst[3]));
        mloc = fmaxf(mloc, __shfl_xor(mloc, 16));
        mloc = fmaxf(mloc, __shfl_xor(mloc, 32));

        // defer-max: skip O-rescale while row max grows by <= 8 (log2 domain)
        if (!__all(mloc - m_run <= 8.0f)) {
            float mnew = fmaxf(m_run, mloc);
            float scp = exp2f(m_run - mnew);
            m_run = mnew;
            l_run *= scp;
            float f0 = __shfl(scp, lg * 4 + 0);
            float f1 = __shfl(scp, lg * 4 + 1);
            float f2_ = __shfl(scp, lg * 4 + 2);
            float f3 = __shfl(scp, lg * 4 + 3);
#pragma unroll
            for (int nd = 0; nd < 4; ++nd) {
                oacc[nd][0] *= f0; oacc[nd][1] *= f1;
                oacc[nd][2] *= f2_; oacc[nd][3] *= f3;
            }
        }

        // exp + tree sum + packed bf16 convert + P store (s ascending in memory)
        float lst[4];
#pragma unroll
        for (int st = 0; st < 4; ++st) {
#pragma unroll
            for (int r = 0; r < 4; ++r)
                p[st][r] = exp2f(p[st][r] - m_run);
            lst[st] = (p[st][0] + p[st][1]) + (p[st][2] + p[st][3]);
            u32x2 pk = { cvt_pk_bf16(p[st][0], p[st][1]), cvt_pk_bf16(p[st][2], p[st][3]) };
            *(u32x2*)(pbase + ((st * 32 + lg * 8) ^ pswz)) = pk;
        }
        float lloc = (lst[0] + lst[1]) + (lst[2] + lst[3]);
        lloc += __shfl_xor(lloc, 16);
        lloc += __shfl_xor(lloc, 32);
        l_run += lloc;

        // ---- PV: O += P * V
        __builtin_amdgcn_s_setprio(1);
#pragma unroll
        for (int c = 0; c < 2; ++c) {
            bf16x8 pa = *(const bf16x8*)(pbase + ((c * 64 + lg * 16) ^ pswz));
#pragma unroll
            for (int nd = 0; nd < 4; ++nd) {
                int row = nd * 16 + lq;
                bf16x8 vf = *(const bf16x8*)(vb + row * 64 + (((c * 4 + lg) ^ (row & 7)) * 8));
                oacc[nd] = __builtin_amdgcn_mfma_f32_16x16x32_bf16(pa, vf, oacc[nd], 0, 0, 0);
            }
        }
        __builtin_amdgcn_s_setprio(0);

        __builtin_amdgcn_sched_barrier(0);
        __builtin_amdgcn_s_barrier();          // all reads of buf done before overwrite
        cur ^= 1;
    }
#undef STAGE

    // epilogue: divide by l (per output row q = lg*4+r), store bf16 (B,T,H*hd)
    float li0 = 1.f / __shfl(l_run, lg * 4 + 0);
    float li1 = 1.f / __shfl(l_run, lg * 4 + 1);
    float li2 = 1.f / __shfl(l_run, lg * 4 + 2);
    float li3 = 1.f / __shfl(l_run, lg * 4 + 3);
#pragma unroll
    for (int nd = 0; nd < 4; ++nd) {
#pragma unroll
        for (int r = 0; r < 4; ++r) {
            int trow = qlo + lg * 4 + r;
            float li = (r == 0) ? li0 : (r == 1) ? li1 : (r == 2) ? li2 : li3;
            attno[((size_t)(b * 2048 + trow)) * 1024 + h * 64 + nd * 16 + lq] =
                f2bf(oacc[nd][r] * li);
        }
    }
}

extern "C" void kernel_launch(void* const* d_in, const int* in_sizes, int n_in,
                              void* d_out, int out_size, void* d_ws, size_t ws_size,
                              hipStream_t stream) {
    const float* x    = (const float*)d_in[0];   // (2,2048,1024)
    const float* Wqkv = (const float*)d_in[1];   // (3072,1024)
    const float* Wout = (const float*)d_in[2];   // (1024,1024)
    float* out = (float*)d_out;

    char* ws = (char*)d_ws;
    u16* xb    = (u16*)(ws + 0);           //  8,388,608 B
    u16* wqkvb = (u16*)(ws + 8388608);     //  6,291,456 B
    u16* woutb = (u16*)(ws + 14680064);    //  2,097,152 B
    u16* qkvb  = (u16*)(ws + 16777216);    // 25,165,824 B
    u16* vtb   = (u16*)(ws + 41943040);    //  8,388,608 B
    u16* attno = (u16*)(ws + 50331648);    //  8,388,608 B  (end 58,720,256)

    cvt_f32_bf16<<<2048, 256, 0, stream>>>(x, xb, 4194304 / 4);
    cvt_f32_bf16<<<2048, 256, 0, stream>>>(Wqkv, wqkvb, 3145728 / 4);
    cvt_f32_bf16<<<1024, 256, 0, stream>>>(Wout, woutb, 1048576 / 4);

    gemm_bt<u16><<<dim3(24, 32), 256, 0, stream>>>(xb, wqkvb, qkvb, 4096, 3072, 1024);

    transpose_v<<<dim3(32, 32), 256, 0, stream>>>(qkvb, vtb);

    fhn_attn<<<1024, 256, 0, stream>>>(qkvb, vtb, attno);

    gemm_bt<float><<<dim3(8, 32), 256, 0, stream>>>(attno, woutb, out, 4096, 1024, 1024);
}

// Round 8
// 129.520 us; speedup vs baseline: 3.1106x; 1.0180x over previous
//
#include <hip/hip_runtime.h>

typedef unsigned short u16;
typedef __attribute__((ext_vector_type(8))) short bf16x8;   // 8 bf16 in 4 VGPRs
typedef __attribute__((ext_vector_type(4))) float f32x4;
typedef __attribute__((ext_vector_type(4))) unsigned short u16x4;
typedef __attribute__((ext_vector_type(2))) unsigned int u32x2;

__device__ __forceinline__ u16 f2bf(float f) {
    unsigned int u = __builtin_bit_cast(unsigned int, f);
    u += 0x7fffu + ((u >> 16) & 1u);          // round-to-nearest-even
    return (u16)(u >> 16);
}

__device__ __forceinline__ float bf2f(u16 b) {
    unsigned int u = ((unsigned int)b) << 16;
    return __builtin_bit_cast(float, u);
}

__device__ __forceinline__ unsigned int cvt_pk_bf16(float lo, float hi) {
    unsigned int r;
    asm("v_cvt_pk_bf16_f32 %0, %1, %2" : "=v"(r) : "v"(lo), "v"(hi));
    return r;                                  // [15:0]=bf16(lo) [31:16]=bf16(hi)
}

__device__ __forceinline__ void gload_lds16(const u16* g, const u16* l) {
    __builtin_amdgcn_global_load_lds((const __attribute__((address_space(1))) void*)g,
                                     (__attribute__((address_space(3))) void*)l,
                                     16, 0, 0);
}

// ---------------- fp32 -> bf16 conversion ----------------
__global__ __launch_bounds__(256) void cvt_f32_bf16(const float* __restrict__ in,
                                                    u16* __restrict__ out, int n4) {
    int i = blockIdx.x * blockDim.x + threadIdx.x;
    int stride = gridDim.x * blockDim.x;
    for (; i < n4; i += stride) {
        float4 v = reinterpret_cast<const float4*>(in)[i];
        u16x4 o = { f2bf(v.x), f2bf(v.y), f2bf(v.z), f2bf(v.w) };
        reinterpret_cast<u16x4*>(out)[i] = o;
    }
}

// ---------------- bf16 GEMM: C[m,n] = sum_k A[m,k] * B[n,k] ----------------
// 128x128 tile, BK=64, 4 waves. 1D grid with bijective XCD chunking:
// blocks sharing an A-panel (same bm) land on the same XCD's L2.
template <typename OutT>
__global__ __launch_bounds__(256) void gemm_bt(const u16* __restrict__ A, const u16* __restrict__ B,
                                               OutT* __restrict__ C, int M, int N, int K) {
    __shared__ u16 ldsA[128 * 64];
    __shared__ u16 ldsB[128 * 64];
    const int tid = threadIdx.x;
    const int lane = tid & 63;
    const int wid = tid >> 6;
    const int wm = wid >> 1, wn = wid & 1;
    const int lq = lane & 15, lg = lane >> 4;

    const int nbn = N >> 7;
    const int id = blockIdx.x;
    const int idp = (id & 7) * ((int)gridDim.x >> 3) + (id >> 3);  // grid%8==0
    const int bm = (idp / nbn) * 128;
    const int bn = (idp % nbn) * 128;

    const u16* aSrc[4];
    const u16* bSrc[4];
    int dstOff[4];
#pragma unroll
    for (int j = 0; j < 4; ++j) {
        int item = j * 256 + tid;
        int row = item >> 3;
        int c16 = item & 7;
        aSrc[j] = A + (size_t)(bm + row) * K + c16 * 8;
        bSrc[j] = B + (size_t)(bn + row) * K + c16 * 8;
        dstOff[j] = (j * 256 + (tid & ~63)) * 16;
    }

    f32x4 acc[4][4] = {};
    for (int k0 = 0; k0 < K; k0 += 64) {
        if (k0) __syncthreads();
#pragma unroll
        for (int j = 0; j < 4; ++j) {
            gload_lds16(aSrc[j], (const u16*)((const char*)ldsA + dstOff[j]));
            gload_lds16(bSrc[j], (const u16*)((const char*)ldsB + dstOff[j]));
            aSrc[j] += 64;
            bSrc[j] += 64;
        }
        __syncthreads();
#pragma unroll
        for (int kk = 0; kk < 2; ++kk) {
            bf16x8 af[4], bfr[4];
#pragma unroll
            for (int m = 0; m < 4; ++m) {
                int row = wm * 64 + m * 16 + lq;
                af[m] = *(const bf16x8*)((const char*)ldsA + row * 128 + kk * 64 + lg * 16);
            }
#pragma unroll
            for (int n = 0; n < 4; ++n) {
                int row = wn * 64 + n * 16 + lq;
                bfr[n] = *(const bf16x8*)((const char*)ldsB + row * 128 + kk * 64 + lg * 16);
            }
#pragma unroll
            for (int m = 0; m < 4; ++m)
#pragma unroll
                for (int n = 0; n < 4; ++n)
                    acc[m][n] = __builtin_amdgcn_mfma_f32_16x16x32_bf16(af[m], bfr[n], acc[m][n], 0, 0, 0);
        }
    }

#pragma unroll
    for (int m = 0; m < 4; ++m) {
#pragma unroll
        for (int n = 0; n < 4; ++n) {
#pragma unroll
            for (int r = 0; r < 4; ++r) {
                int row = bm + wm * 64 + m * 16 + lg * 4 + r;
                int col = bn + wn * 64 + n * 16 + lq;
                float v = acc[m][n][r];
                if constexpr (sizeof(OutT) == 2)
                    C[(size_t)row * N + col] = (OutT)f2bf(v);
                else
                    C[(size_t)row * N + col] = (OutT)v;
            }
        }
    }
}

// ---------------- transpose V: (B,T,[v]H,hd) -> (B,H,hd,T) ----------------
__global__ __launch_bounds__(256) void transpose_v(const u16* __restrict__ qkv, u16* __restrict__ vt) {
    __shared__ u16 tile[64][72];
    const int tb = blockIdx.x * 64;
    const int bh = blockIdx.y;
    const int b = bh >> 4, h = bh & 15;
    const u16* src = qkv + ((size_t)(b * 2048 + tb)) * 3072 + 2048 + h * 64;
    const int tid = threadIdx.x;
#pragma unroll
    for (int p = 0; p < 2; ++p) {
        int item = p * 256 + tid;
        int t = item >> 3, c = item & 7;
        bf16x8 v = *(const bf16x8*)(src + (size_t)t * 3072 + c * 8);
        *(bf16x8*)(&tile[t][c * 8]) = v;
    }
    __syncthreads();
    u16* dst = vt + ((size_t)bh * 64) * 2048 + tb;
#pragma unroll
    for (int p = 0; p < 2; ++p) {
        int item = p * 256 + tid;
        int d = item >> 3, tc = item & 7;
        bf16x8 o;
#pragma unroll
        for (int j = 0; j < 8; ++j) o[j] = (short)tile[tc * 8 + j][d];
        *(bf16x8*)(dst + (size_t)d * 2048 + tc * 8) = o;
    }
}

// ---------------- flash attention, causal, hd=64, LDS-staged K/V ----------------
// 1D grid 1024; bh -> XCD (bh>>2) so each XCD's L2 holds its 4 heads' K/V (2 MB).
// Block: 4 waves x 16 q-rows = 64-row q tile; LDS 40 KB -> 4 blocks/CU resident.
// Single barrier per kv-iteration: {vmcnt(0); barrier; STAGE(next); compute(cur)}.
__global__ __launch_bounds__(256, 4) void fhn_attn(const u16* __restrict__ qkv, const u16* __restrict__ vt,
                                                   u16* __restrict__ attno) {
    __shared__ u16 kvbuf[2][2][64 * 64];      // [dbuf][0=K,1=V][row][chunk swizzled]  32 KB
    __shared__ u16 plds[4][16][64];           // per-wave P tile, XOR-swizzled          8 KB
    // id%8 = XCD; give XCD x the 4 heads bh = x*4..x*4+3; tile = id>>5.
    const int id = blockIdx.x;
    const int bh = (id & 7) * 4 + ((id >> 3) & 3);
    const int tile = id >> 5;
    const int qt = (bh & 1) ? tile : (31 - tile);   // alternate ordering for balance
    const int b = bh >> 4, h = bh & 15;
    const int tid = threadIdx.x;
    const int w = tid >> 6;
    const int lane = tid & 63;
    const int lq = lane & 15, lg = lane >> 4;
    const int qlo = qt * 64 + w * 16;         // wave's first q row
    const int tq = qlo + lq;                  // softmax row owned by this lane

    // Q fragments (B-operand of swapped QK^T), pre-scaled by log2(e)/sqrt(64)
    bf16x8 qf[2];
    {
        const u16* qrow = qkv + ((size_t)(b * 2048 + tq)) * 3072 + h * 64;
        qf[0] = *(const bf16x8*)(qrow + lg * 8);
        qf[1] = *(const bf16x8*)(qrow + 32 + lg * 8);
#pragma unroll
        for (int kk = 0; kk < 2; ++kk)
#pragma unroll
            for (int j = 0; j < 8; ++j)
                qf[kk][j] = (short)f2bf(bf2f((u16)qf[kk][j]) * 0.1803368801f);
    }

    // staging: 64 rows x 8 chunks(16B) per tile; 2 chunks/thread for K and V each.
    // LDS[row][c] = G[row][c ^ (row&7)]  (pre-swizzled global source, linear LDS dest)
    const int it0 = tid, it1 = 256 + tid;
    const int r0 = it0 >> 3, g0 = (it0 & 7) ^ (r0 & 7);
    const int r1 = it1 >> 3, g1 = (it1 & 7) ^ (r1 & 7);
    const u16* kS0 = qkv + ((size_t)(b * 2048 + r0)) * 3072 + 1024 + h * 64 + g0 * 8;
    const u16* kS1 = qkv + ((size_t)(b * 2048 + r1)) * 3072 + 1024 + h * 64 + g1 * 8;
    const u16* vS0 = vt + ((size_t)bh * 64 + r0) * 2048 + g0 * 8;
    const u16* vS1 = vt + ((size_t)bh * 64 + r1) * 2048 + g1 * 8;
    const int d0 = (it0 & ~63) * 8;           // wave-uniform LDS element base
    const int d1 = (it1 & ~63) * 8;

#define STAGE(buf)                                            \
    do {                                                      \
        gload_lds16(kS0, &kvbuf[buf][0][d0]);                 \
        gload_lds16(kS1, &kvbuf[buf][0][d1]);                 \
        gload_lds16(vS0, &kvbuf[buf][1][d0]);                 \
        gload_lds16(vS1, &kvbuf[buf][1][d1]);                 \
        kS0 += 64 * 3072; kS1 += 64 * 3072;                   \
        vS0 += 64; vS1 += 64;                                 \
    } while (0)

    const int nkv = qt + 1;
    float m_run = -1e30f, l_run = 0.f;
    f32x4 oacc[4] = {};
    int cur = 0;

    char* const pbase = (char*)&plds[w][0][0] + lq * 128;
    const int pswz = (lq & 7) << 4;

    STAGE(0);                                  // prefetch jb=0

    for (int jb = 0; jb < nkv; ++jb) {
        // current tile's loads (issued last iter) are the only outstanding vmem
        asm volatile("s_waitcnt vmcnt(0)" ::: "memory");
        __builtin_amdgcn_s_barrier();          // also: everyone finished reading cur^1
        __builtin_amdgcn_sched_barrier(0);
        if (jb + 1 < nkv) STAGE(cur ^ 1);      // overwrite freed buffer; lands under compute

        const u16* kb = kvbuf[cur][0];
        const u16* vb = kvbuf[cur][1];

        // ---- QK^T (swapped): S^T = K * Q^T, scores already in log2 units
        float p[4][4];
        __builtin_amdgcn_s_setprio(1);
#pragma unroll
        for (int st = 0; st < 4; ++st) {
            int row = st * 16 + lq;
            f32x4 sacc = {};
            sacc = __builtin_amdgcn_mfma_f32_16x16x32_bf16(
                *(const bf16x8*)(kb + row * 64 + ((lg ^ (row & 7)) * 8)), qf[0], sacc, 0, 0, 0);
            sacc = __builtin_amdgcn_mfma_f32_16x16x32_bf16(
                *(const bf16x8*)(kb + row * 64 + (((4 + lg) ^ (row & 7)) * 8)), qf[1], sacc, 0, 0, 0);
#pragma unroll
            for (int r = 0; r < 4; ++r) p[st][r] = sacc[r];
        }
        __builtin_amdgcn_s_setprio(0);

        // V fragments now: ds_read latency hides under the softmax VALU chain
        bf16x8 vf[2][4];
#pragma unroll
        for (int c = 0; c < 2; ++c)
#pragma unroll
            for (int nd = 0; nd < 4; ++nd) {
                int row = nd * 16 + lq;
                vf[c][nd] = *(const bf16x8*)(vb + row * 64 + (((c * 4 + lg) ^ (row & 7)) * 8));
            }

        if (jb == qt) {                        // block-uniform: mask only diagonal tile
#pragma unroll
            for (int st = 0; st < 4; ++st)
#pragma unroll
                for (int r = 0; r < 4; ++r) {
                    int s = jb * 64 + st * 16 + lg * 4 + r;
                    if (s > tq) p[st][r] = -1e30f;
                }
        }

        // tree max (depth 4 instead of 16-deep serial chain)
        float mst[4];
#pragma unroll
        for (int st = 0; st < 4; ++st)
            mst[st] = fmaxf(fmaxf(p[st][0], p[st][1]), fmaxf(p[st][2], p[st][3]));
        float mloc = fmaxf(fmaxf(mst[0], mst[1]), fmaxf(mst[2], mst[3]));
        mloc = fmaxf(mloc, __shfl_xor(mloc, 16));
        mloc = fmaxf(mloc, __shfl_xor(mloc, 32));

        // defer-max: skip O-rescale while row max grows by <= 8 (log2 domain)
        if (!__all(mloc - m_run <= 8.0f)) {
            float mnew = fmaxf(m_run, mloc);
            float scp = exp2f(m_run - mnew);
            m_run = mnew;
            l_run *= scp;
            float f0 = __shfl(scp, lg * 4 + 0);
            float f1 = __shfl(scp, lg * 4 + 1);
            float f2_ = __shfl(scp, lg * 4 + 2);
            float f3 = __shfl(scp, lg * 4 + 3);
#pragma unroll
            for (int nd = 0; nd < 4; ++nd) {
                oacc[nd][0] *= f0; oacc[nd][1] *= f1;
                oacc[nd][2] *= f2_; oacc[nd][3] *= f3;
            }
        }

        // exp + tree sum + packed bf16 convert + P store (s ascending in memory)
        float lst[4];
#pragma unroll
        for (int st = 0; st < 4; ++st) {
#pragma unroll
            for (int r = 0; r < 4; ++r)
                p[st][r] = exp2f(p[st][r] - m_run);
            lst[st] = (p[st][0] + p[st][1]) + (p[st][2] + p[st][3]);
            u32x2 pk = { cvt_pk_bf16(p[st][0], p[st][1]), cvt_pk_bf16(p[st][2], p[st][3]) };
            *(u32x2*)(pbase + ((st * 32 + lg * 8) ^ pswz)) = pk;
        }
        float lloc = (lst[0] + lst[1]) + (lst[2] + lst[3]);
        lloc += __shfl_xor(lloc, 16);
        lloc += __shfl_xor(lloc, 32);
        l_run += lloc;

        // ---- PV: O += P * V
        __builtin_amdgcn_s_setprio(1);
#pragma unroll
        for (int c = 0; c < 2; ++c) {
            bf16x8 pa = *(const bf16x8*)(pbase + ((c * 64 + lg * 16) ^ pswz));
#pragma unroll
            for (int nd = 0; nd < 4; ++nd)
                oacc[nd] = __builtin_amdgcn_mfma_f32_16x16x32_bf16(pa, vf[c][nd], oacc[nd], 0, 0, 0);
        }
        __builtin_amdgcn_s_setprio(0);

        cur ^= 1;
    }
#undef STAGE

    // epilogue: divide by l (per output row q = lg*4+r), store bf16 (B,T,H*hd)
    float li0 = 1.f / __shfl(l_run, lg * 4 + 0);
    float li1 = 1.f / __shfl(l_run, lg * 4 + 1);
    float li2 = 1.f / __shfl(l_run, lg * 4 + 2);
    float li3 = 1.f / __shfl(l_run, lg * 4 + 3);
#pragma unroll
    for (int nd = 0; nd < 4; ++nd) {
#pragma unroll
        for (int r = 0; r < 4; ++r) {
            int trow = qlo + lg * 4 + r;
            float li = (r == 0) ? li0 : (r == 1) ? li1 : (r == 2) ? li2 : li3;
            attno[((size_t)(b * 2048 + trow)) * 1024 + h * 64 + nd * 16 + lq] =
                f2bf(oacc[nd][r] * li);
        }
    }
}

extern "C" void kernel_launch(void* const* d_in, const int* in_sizes, int n_in,
                              void* d_out, int out_size, void* d_ws, size_t ws_size,
                              hipStream_t stream) {
    const float* x    = (const float*)d_in[0];   // (2,2048,1024)
    const float* Wqkv = (const float*)d_in[1];   // (3072,1024)
    const float* Wout = (const float*)d_in[2];   // (1024,1024)
    float* out = (float*)d_out;

    char* ws = (char*)d_ws;
    u16* xb    = (u16*)(ws + 0);           //  8,388,608 B
    u16* wqkvb = (u16*)(ws + 8388608);     //  6,291,456 B
    u16* woutb = (u16*)(ws + 14680064);    //  2,097,152 B
    u16* qkvb  = (u16*)(ws + 16777216);    // 25,165,824 B
    u16* vtb   = (u16*)(ws + 41943040);    //  8,388,608 B
    u16* attno = (u16*)(ws + 50331648);    //  8,388,608 B  (end 58,720,256)

    cvt_f32_bf16<<<2048, 256, 0, stream>>>(x, xb, 4194304 / 4);
    cvt_f32_bf16<<<2048, 256, 0, stream>>>(Wqkv, wqkvb, 3145728 / 4);
    cvt_f32_bf16<<<1024, 256, 0, stream>>>(Wout, woutb, 1048576 / 4);

    gemm_bt<u16><<<768, 256, 0, stream>>>(xb, wqkvb, qkvb, 4096, 3072, 1024);

    transpose_v<<<dim3(32, 32), 256, 0, stream>>>(qkvb, vtb);

    fhn_attn<<<1024, 256, 0, stream>>>(qkvb, vtb, attno);

    gemm_bt<float><<<256, 256, 0, stream>>>(attno, woutb, out, 4096, 1024, 1024);
}